// Round 1
// baseline (516.318 us; speedup 1.0000x reference)
//
#include <hip/hip_runtime.h>
#include <math.h>

#define HH 1024
#define WW 1024
#define NB 16
#define NPAIR 8
#define NBINS 725
#define NPIX (HH*WW)

#define NBLK3 128
#define PIX3 (NPIX / (NBLK3*256))   // 32

__device__ __forceinline__ float2 cmul(float2 a, float2 b) {
    return make_float2(a.x*b.x - a.y*b.y, a.x*b.y + a.y*b.x);
}

// In-LDS radix-2 DIT FFT of 1024 complex points. Data must be loaded
// bit-reversed; output natural order. 256 threads, all call uniformly.
__device__ void fft1024(float2* buf, int tid) {
    for (int s = 1; s <= 10; ++s) {
        const int m = 1 << s, half = m >> 1;
        const float ang_scale = -6.283185307179586f / (float)m;
        #pragma unroll
        for (int r = 0; r < 2; ++r) {
            int t = tid + r * 256;            // butterfly id 0..511
            int j = t & (half - 1);
            int grp = t >> (s - 1);
            int i1 = grp * m + j;
            int i2 = i1 + half;
            float sn, cs;
            sincosf(ang_scale * (float)j, &sn, &cs);
            float2 u = buf[i1], v = buf[i2];
            float2 vw = cmul(v, make_float2(cs, sn));
            buf[i1] = make_float2(u.x + vw.x, u.y + vw.y);
            buf[i2] = make_float2(u.x - vw.x, u.y - vw.y);
        }
        __syncthreads();
    }
}

// Pass 1: row FFTs. Block = (pair p, row y). Packs batch 2p (real) + 2p+1 (imag).
__global__ __launch_bounds__(256) void fft_rows(const float* __restrict__ in,
                                                float2* __restrict__ spec) {
    __shared__ float2 buf[1024];
    int blk = blockIdx.x;
    int p = blk >> 10, y = blk & 1023;
    const float* xrow = in + (((size_t)(2 * p)) << 20) + (size_t)y * WW;
    const float* yrow = in + (((size_t)(2 * p + 1)) << 20) + (size_t)y * WW;
    int tid = threadIdx.x;
    for (int i = tid; i < 1024; i += 256) {
        int r = (int)(__brev((unsigned)i) >> 22);
        buf[r] = make_float2(xrow[i], yrow[i]);
    }
    __syncthreads();
    fft1024(buf, tid);
    float2* orow = spec + (((size_t)p) << 20) + (size_t)y * WW;
    for (int i = tid; i < 1024; i += 256) orow[i] = buf[i];
}

// Pass 2: column FFTs, in place. Block = (pair p, column x).
__global__ __launch_bounds__(256) void fft_cols(float2* __restrict__ spec) {
    __shared__ float2 buf[1024];
    int blk = blockIdx.x;
    int p = blk >> 10, x = blk & 1023;
    float2* base = spec + (((size_t)p) << 20) + x;
    int tid = threadIdx.x;
    for (int i = tid; i < 1024; i += 256) {
        int r = (int)(__brev((unsigned)i) >> 22);
        buf[r] = base[(size_t)i * WW];
    }
    __syncthreads();
    fft1024(buf, tid);
    for (int i = tid; i < 1024; i += 256) base[(size_t)i * WW] = buf[i];
}

__device__ __forceinline__ int radial_bin(int ky, int kx) {
    int dy = ky - 512, dx = kx - 512;
    int d2 = dy * dy + dx * dx;
    int bin = (int)sqrtf((float)d2);
    if ((bin + 1) * (bin + 1) <= d2) ++bin;
    else if (bin * bin > d2) --bin;
    return bin;
}

// Recover per-batch powers from packed spectrum at pixel j and mirror jm.
__device__ __forceinline__ void pair_powers(const float2* __restrict__ spec,
                                            int p, size_t j, size_t jm,
                                            float* px, float* py) {
    float2 f1 = spec[(((size_t)p) << 20) + j];
    float2 f2 = spec[(((size_t)p) << 20) + jm];
    float xr = 0.5f * (f1.x + f2.x), xi = 0.5f * (f1.y - f2.y);
    float yr = 0.5f * (f1.y + f2.y), yi = 0.5f * (f2.x - f1.x);
    const float inv = 1.0f / (float)NPIX;
    *px = (xr * xr + xi * xi) * inv;
    *py = (yr * yr + yi * yi) * inv;
}

// Pass 3: radial bin sums + counts via LDS histograms, global atomic merge.
__global__ __launch_bounds__(256) void radial_hist(const float2* __restrict__ spec,
                                                   float* __restrict__ sums,
                                                   float* __restrict__ counts) {
    __shared__ float hs[NB * NBINS];
    __shared__ float hc[NBINS];
    int tid = threadIdx.x;
    for (int i = tid; i < NB * NBINS; i += 256) hs[i] = 0.f;
    for (int i = tid; i < NBINS; i += 256) hc[i] = 0.f;
    __syncthreads();
    int base = blockIdx.x * (256 * PIX3);
    for (int q = 0; q < PIX3; ++q) {
        int j = base + q * 256 + tid;
        int ky = j >> 10, kx = j & 1023;
        int bin = radial_bin(ky, kx);
        atomicAdd(&hc[bin], 1.0f);
        int my = (HH - ky) & 1023, mx = (WW - kx) & 1023;
        size_t jm = (((size_t)my) << 10) + (size_t)mx;
        for (int p = 0; p < NPAIR; ++p) {
            float px, py;
            pair_powers(spec, p, (size_t)j, jm, &px, &py);
            atomicAdd(&hs[(2 * p) * NBINS + bin], px);
            atomicAdd(&hs[(2 * p + 1) * NBINS + bin], py);
        }
    }
    __syncthreads();
    for (int i = tid; i < NB * NBINS; i += 256)
        if (hs[i] != 0.f) atomicAdd(&sums[i], hs[i]);
    for (int i = tid; i < NBINS; i += 256)
        if (hc[i] != 0.f) atomicAdd(&counts[i], hc[i]);
}

// Pass 4: radial[b][k] = counts[k]>0 ? sums/max(counts,1) : 0
__global__ __launch_bounds__(256) void finalize_radial(const float* __restrict__ sums,
                                                       const float* __restrict__ counts,
                                                       float* __restrict__ radial) {
    int i = blockIdx.x * 256 + threadIdx.x;
    if (i < NB * NBINS) {
        float c = counts[i % NBINS];
        radial[i] = (c > 0.f) ? sums[i] / fmaxf(c, 1.f) : 0.f;
    }
}

// Pass 5: loss = (WA/B) * sum over all pixels/batches of (P - radial + EPS)^2
__global__ __launch_bounds__(256) void loss_kernel(const float2* __restrict__ spec,
                                                   const float* __restrict__ radial,
                                                   float* __restrict__ out) {
    int tid = threadIdx.x;
    float acc = 0.f;
    int base = blockIdx.x * (256 * PIX3);
    for (int q = 0; q < PIX3; ++q) {
        int j = base + q * 256 + tid;
        int ky = j >> 10, kx = j & 1023;
        int bin = radial_bin(ky, kx);
        int my = (HH - ky) & 1023, mx = (WW - kx) & 1023;
        size_t jm = (((size_t)my) << 10) + (size_t)mx;
        for (int p = 0; p < NPAIR; ++p) {
            float px, py;
            pair_powers(spec, p, (size_t)j, jm, &px, &py);
            float dx_ = px - radial[(2 * p) * NBINS + bin] + 1e-12f;
            float dy_ = py - radial[(2 * p + 1) * NBINS + bin] + 1e-12f;
            acc += dx_ * dx_ + dy_ * dy_;
        }
    }
    __shared__ float red[256];
    red[tid] = acc;
    __syncthreads();
    for (int s = 128; s > 0; s >>= 1) {
        if (tid < s) red[tid] += red[tid + s];
        __syncthreads();
    }
    if (tid == 0) atomicAdd(out, red[0] * (0.002f / 16.0f));
}

extern "C" void kernel_launch(void* const* d_in, const int* in_sizes, int n_in,
                              void* d_out, int out_size, void* d_ws, size_t ws_size,
                              hipStream_t stream) {
    const float* in = (const float*)d_in[0];
    float* out = (float*)d_out;
    char* ws = (char*)d_ws;

    float2* spec  = (float2*)ws;                                  // 64 MiB
    float* sums   = (float*)(ws + ((size_t)NPAIR << 20) * sizeof(float2));
    float* counts = sums + NB * NBINS;
    float* radial = counts + NBINS;

    hipMemsetAsync(sums, 0, (size_t)(NB * NBINS + NBINS) * sizeof(float), stream);
    hipMemsetAsync(out, 0, sizeof(float), stream);

    fft_rows<<<NPAIR * 1024, 256, 0, stream>>>(in, spec);
    fft_cols<<<NPAIR * 1024, 256, 0, stream>>>(spec);
    radial_hist<<<NBLK3, 256, 0, stream>>>(spec, sums, counts);
    finalize_radial<<<(NB * NBINS + 255) / 256, 256, 0, stream>>>(sums, counts, radial);
    loss_kernel<<<NBLK3, 256, 0, stream>>>(spec, radial, out);
}

// Round 2
// 282.005 us; speedup vs baseline: 1.8309x; 1.8309x over previous
//
#include <hip/hip_runtime.h>
#include <math.h>

#define HH 1024
#define WW 1024
#define NB 16
#define NPAIR 8
#define NBINS 725
#define NPIX (HH*WW)
#define TWO_PI 6.283185307179586f

__device__ __forceinline__ int radial_bin(int ky, int kx) {
    int dy = ky - 512, dx = kx - 512;
    int d2 = dy * dy + dx * dx;
    int bin = (int)sqrtf((float)d2);
    if ((bin + 1) * (bin + 1) <= d2) ++bin;
    else if (bin * bin > d2) --bin;
    return bin;
}

__device__ __forceinline__ void make_tw(float2* tw, int tid) {
    for (int i = tid; i < 512; i += 256) {
        float sn, cs;
        sincosf(-TWO_PI * (float)i * (1.0f / 1024.0f), &sn, &cs);
        tw[i] = make_float2(cs, sn);
    }
}

// Pass 1: row FFTs. Block = (pair p, row y). Packs batch 2p (real) + 2p+1 (imag).
__global__ __launch_bounds__(256) void fft_rows(const float* __restrict__ in,
                                                float2* __restrict__ spec) {
    __shared__ float2 buf[1024];
    __shared__ float2 tw[512];
    int tid = threadIdx.x;
    make_tw(tw, tid);
    int blk = blockIdx.x;
    int p = blk >> 10, y = blk & 1023;
    const float* xrow = in + (((size_t)(2 * p)) << 20) + ((size_t)y << 10);
    const float* yrow = xrow + (1u << 20);
    for (int i = tid; i < 1024; i += 256) {
        int r = (int)(__brev((unsigned)i) >> 22);
        buf[r] = make_float2(xrow[i], yrow[i]);
    }
    __syncthreads();
    for (int s = 1; s <= 10; ++s) {
        int half = 1 << (s - 1);
        #pragma unroll
        for (int r = 0; r < 2; ++r) {
            int t = tid + (r << 8);
            int j = t & (half - 1);
            int i1 = ((t >> (s - 1)) << s) + j;
            int i2 = i1 + half;
            float2 w = tw[j << (10 - s)];
            float2 u = buf[i1], v = buf[i2];
            float2 vw = make_float2(v.x * w.x - v.y * w.y, v.x * w.y + v.y * w.x);
            buf[i1] = make_float2(u.x + vw.x, u.y + vw.y);
            buf[i2] = make_float2(u.x - vw.x, u.y - vw.y);
        }
        __syncthreads();
    }
    float2* orow = spec + (((size_t)p) << 20) + ((size_t)y << 10);
    for (int i = tid; i < 1024; i += 256) orow[i] = buf[i];
}

// Pass 2: column FFTs, 8 columns per block through a padded LDS tile.
#define CST 9
__global__ __launch_bounds__(256) void fft_cols(float2* __restrict__ spec) {
    __shared__ float2 buf[1024 * CST];
    __shared__ float2 tw[512];
    int tid = threadIdx.x;
    make_tw(tw, tid);
    int blk = blockIdx.x;
    int p = blk >> 7, x0 = (blk & 127) << 3;
    float2* base = spec + (((size_t)p) << 20) + x0;
    for (int idx = tid; idx < 8192; idx += 256) {
        int i = idx >> 3, c = idx & 7;
        int r = (int)(__brev((unsigned)i) >> 22);
        buf[r * CST + c] = base[((size_t)i << 10) + c];
    }
    __syncthreads();
    int c = tid & 7, bfb = tid >> 3;
    for (int s = 1; s <= 10; ++s) {
        int half = 1 << (s - 1);
        #pragma unroll
        for (int r = 0; r < 16; ++r) {
            int bf = bfb + (r << 5);
            int j = bf & (half - 1);
            int i1 = ((bf >> (s - 1)) << s) + j;
            int i2 = i1 + half;
            float2 w = tw[j << (10 - s)];
            float2 u = buf[i1 * CST + c], v = buf[i2 * CST + c];
            float2 vw = make_float2(v.x * w.x - v.y * w.y, v.x * w.y + v.y * w.x);
            buf[i1 * CST + c] = make_float2(u.x + vw.x, u.y + vw.y);
            buf[i2 * CST + c] = make_float2(u.x - vw.x, u.y - vw.y);
        }
        __syncthreads();
    }
    for (int idx = tid; idx < 8192; idx += 256) {
        int i = idx >> 3, cc = idx & 7;
        base[((size_t)i << 10) + cc] = buf[i * CST + cc];
    }
}

// Recover per-batch powers from packed spectrum values f1=F[j], f2=F[jm].
__device__ __forceinline__ void pair_powers2(float2 f1, float2 f2,
                                             float* px, float* py) {
    float xr = 0.5f * (f1.x + f2.x), xi = 0.5f * (f1.y - f2.y);
    float yr = 0.5f * (f1.y + f2.y), yi = 0.5f * (f2.x - f1.x);
    const float inv = 1.0f / (float)NPIX;
    *px = (xr * xr + xi * xi) * inv;
    *py = (yr * yr + yi * yi) * inv;
}

// Pass 3: radial bin sums per pair-block (8 rows each), small LDS hist.
__global__ __launch_bounds__(256) void radial_hist(const float2* __restrict__ spec,
                                                   float* __restrict__ sums,
                                                   float* __restrict__ counts) {
    __shared__ float hs0[NBINS], hs1[NBINS], hc[NBINS];
    int tid = threadIdx.x;
    int blk = blockIdx.x;
    int p = blk >> 7, rc = blk & 127;
    for (int i = tid; i < NBINS; i += 256) { hs0[i] = 0.f; hs1[i] = 0.f; hc[i] = 0.f; }
    __syncthreads();
    const float2* sp = spec + (((size_t)p) << 20);
    for (int q = 0; q < 32; ++q) {
        int idx = (q << 8) + tid;                 // 0..8191
        int ky = (rc << 3) + (idx >> 10);
        int kx = idx & 1023;
        int bin = radial_bin(ky, kx);
        int my = (1024 - ky) & 1023, mx = (1024 - kx) & 1023;
        float2 f1 = sp[((size_t)ky << 10) + kx];
        float2 f2 = sp[((size_t)my << 10) + mx];
        float px, py;
        pair_powers2(f1, f2, &px, &py);
        atomicAdd(&hs0[bin], px);
        atomicAdd(&hs1[bin], py);
        if (p == 0) atomicAdd(&hc[bin], 1.0f);
    }
    __syncthreads();
    for (int i = tid; i < NBINS; i += 256) {
        if (hs0[i] != 0.f) atomicAdd(&sums[(2 * p) * NBINS + i], hs0[i]);
        if (hs1[i] != 0.f) atomicAdd(&sums[(2 * p + 1) * NBINS + i], hs1[i]);
        if (p == 0 && hc[i] != 0.f) atomicAdd(&counts[i], hc[i]);
    }
}

// Pass 4: radial[b][k] = counts[k]>0 ? sums/max(counts,1) : 0
__global__ __launch_bounds__(256) void finalize_radial(const float* __restrict__ sums,
                                                       const float* __restrict__ counts,
                                                       float* __restrict__ radial) {
    int i = blockIdx.x * 256 + threadIdx.x;
    if (i < NB * NBINS) {
        float c = counts[i % NBINS];
        radial[i] = (c > 0.f) ? sums[i] / fmaxf(c, 1.f) : 0.f;
    }
}

// Pass 5: loss accumulation, pair-split, radial rows preloaded in LDS.
__global__ __launch_bounds__(256) void loss_kernel(const float2* __restrict__ spec,
                                                   const float* __restrict__ radial,
                                                   float* __restrict__ out) {
    __shared__ float r0[NBINS], r1[NBINS];
    __shared__ float red[256];
    int tid = threadIdx.x, blk = blockIdx.x;
    int p = blk >> 7, rc = blk & 127;
    for (int i = tid; i < NBINS; i += 256) {
        r0[i] = radial[(2 * p) * NBINS + i];
        r1[i] = radial[(2 * p + 1) * NBINS + i];
    }
    __syncthreads();
    const float2* sp = spec + (((size_t)p) << 20);
    float acc = 0.f;
    for (int q = 0; q < 32; ++q) {
        int idx = (q << 8) + tid;
        int ky = (rc << 3) + (idx >> 10);
        int kx = idx & 1023;
        int bin = radial_bin(ky, kx);
        int my = (1024 - ky) & 1023, mx = (1024 - kx) & 1023;
        float2 f1 = sp[((size_t)ky << 10) + kx];
        float2 f2 = sp[((size_t)my << 10) + mx];
        float px, py;
        pair_powers2(f1, f2, &px, &py);
        float dx_ = px - r0[bin] + 1e-12f;
        float dy_ = py - r1[bin] + 1e-12f;
        acc += dx_ * dx_ + dy_ * dy_;
    }
    red[tid] = acc;
    __syncthreads();
    for (int s = 128; s > 0; s >>= 1) {
        if (tid < s) red[tid] += red[tid + s];
        __syncthreads();
    }
    if (tid == 0) atomicAdd(out, red[0] * (0.002f / 16.0f));
}

extern "C" void kernel_launch(void* const* d_in, const int* in_sizes, int n_in,
                              void* d_out, int out_size, void* d_ws, size_t ws_size,
                              hipStream_t stream) {
    const float* in = (const float*)d_in[0];
    float* out = (float*)d_out;
    char* ws = (char*)d_ws;

    float2* spec  = (float2*)ws;                                  // 64 MiB
    float* sums   = (float*)(ws + ((size_t)NPAIR << 20) * sizeof(float2));
    float* counts = sums + NB * NBINS;
    float* radial = counts + NBINS;

    hipMemsetAsync(sums, 0, (size_t)(NB * NBINS + NBINS) * sizeof(float), stream);
    hipMemsetAsync(out, 0, sizeof(float), stream);

    fft_rows<<<NPAIR * 1024, 256, 0, stream>>>(in, spec);
    fft_cols<<<NPAIR * 128, 256, 0, stream>>>(spec);
    radial_hist<<<NPAIR * 128, 256, 0, stream>>>(spec, sums, counts);
    finalize_radial<<<(NB * NBINS + 255) / 256, 256, 0, stream>>>(sums, counts, radial);
    loss_kernel<<<NPAIR * 128, 256, 0, stream>>>(spec, radial, out);
}

// Round 3
// 263.029 us; speedup vs baseline: 1.9630x; 1.0721x over previous
//
#include <hip/hip_runtime.h>
#include <math.h>

#define NB 16
#define NPAIR 8
#define NBINS 725
#define NPIX (1024*1024)
#define TWO_PI 6.283185307179586f
#define CST 9

__device__ __forceinline__ int radial_bin(int ky, int kx) {
    int dy = ky - 512, dx = kx - 512;
    int d2 = dy * dy + dx * dx;
    int bin = (int)sqrtf((float)d2);
    if ((bin + 1) * (bin + 1) <= d2) ++bin;
    else if (bin * bin > d2) --bin;
    return bin;
}

__device__ __forceinline__ void make_tw(float2* tw, int tid) {
    for (int i = tid; i < 512; i += 256) {
        float sn, cs;
        sincosf(-TWO_PI * (float)i * (1.0f / 1024.0f), &sn, &cs);
        tw[i] = make_float2(cs, sn);
    }
}

// Mirror-paired column groups: block k owns 8 columns such that for every
// owned column c, column (1024-c)&1023 is also owned.
__device__ __forceinline__ int col_of(int k, int c) {
    if (k == 0) return (c < 4) ? c : ((c == 4) ? 512 : 1028 - c); // {0,1,2,3,512,1023,1022,1021}
    int a = k << 2;
    return (c < 4) ? (a + c) : (1017 + c - a);   // {a..a+3, 1021-a..1024-a}
}
__device__ __forceinline__ int mir_of(int k, int c) {            // local index of mirror column
    if (k == 0) return (c == 0 || c == 4) ? c : ((c < 4) ? c + 4 : c - 4);
    return 7 - c;
}

// Pass 1: row FFTs. Block = (pair p, row y). Packs batch 2p (real) + 2p+1 (imag).
__global__ __launch_bounds__(256) void fft_rows(const float* __restrict__ in,
                                                float2* __restrict__ spec) {
    __shared__ float2 buf[1024];
    __shared__ float2 tw[512];
    int tid = threadIdx.x;
    make_tw(tw, tid);
    int blk = blockIdx.x;
    int p = blk >> 10, y = blk & 1023;
    const float* xrow = in + (((size_t)(2 * p)) << 20) + ((size_t)y << 10);
    const float* yrow = xrow + (1u << 20);
    for (int i = tid; i < 1024; i += 256) {
        int r = (int)(__brev((unsigned)i) >> 22);
        buf[r] = make_float2(xrow[i], yrow[i]);
    }
    __syncthreads();
    for (int s = 1; s <= 10; ++s) {
        int half = 1 << (s - 1);
        #pragma unroll
        for (int r = 0; r < 2; ++r) {
            int t = tid + (r << 8);
            int j = t & (half - 1);
            int i1 = ((t >> (s - 1)) << s) + j;
            int i2 = i1 + half;
            float2 w = tw[j << (10 - s)];
            float2 u = buf[i1], v = buf[i2];
            float2 vw = make_float2(v.x * w.x - v.y * w.y, v.x * w.y + v.y * w.x);
            buf[i1] = make_float2(u.x + vw.x, u.y + vw.y);
            buf[i2] = make_float2(u.x - vw.x, u.y - vw.y);
        }
        __syncthreads();
    }
    float2* orow = spec + (((size_t)p) << 20) + ((size_t)y << 10);
    for (int i = tid; i < 1024; i += 256) orow[i] = buf[i];
}

// Pass 2: column FFTs on mirror-paired column groups; computes per-batch
// powers via Hermitian split and overwrites spec cells in place with
// float2(power_even_batch, power_odd_batch).
__global__ __launch_bounds__(256) void fft_cols_pow(float2* __restrict__ spec) {
    __shared__ float2 buf[1024 * CST];
    __shared__ float2 tw[512];
    int tid = threadIdx.x;
    make_tw(tw, tid);
    int blk = blockIdx.x;
    int p = blk >> 7, k = blk & 127;
    float2* base = spec + (((size_t)p) << 20);
    for (int idx = tid; idx < 8192; idx += 256) {
        int i = idx >> 3, c = idx & 7;
        int r = (int)(__brev((unsigned)i) >> 22);
        buf[r * CST + c] = base[((size_t)i << 10) + col_of(k, c)];
    }
    __syncthreads();
    int c = tid & 7, bfb = tid >> 3;
    for (int s = 1; s <= 10; ++s) {
        int half = 1 << (s - 1);
        #pragma unroll
        for (int r = 0; r < 16; ++r) {
            int bf = bfb + (r << 5);
            int j = bf & (half - 1);
            int i1 = ((bf >> (s - 1)) << s) + j;
            int i2 = i1 + half;
            float2 w = tw[j << (10 - s)];
            float2 u = buf[i1 * CST + c], v = buf[i2 * CST + c];
            float2 vw = make_float2(v.x * w.x - v.y * w.y, v.x * w.y + v.y * w.x);
            buf[i1 * CST + c] = make_float2(u.x + vw.x, u.y + vw.y);
            buf[i2 * CST + c] = make_float2(u.x - vw.x, u.y - vw.y);
        }
        __syncthreads();
    }
    const float inv = 1.0f / (float)NPIX;
    for (int idx = tid; idx < 8192; idx += 256) {
        int ky = idx >> 3, cc = idx & 7;
        int my = (1024 - ky) & 1023;
        float2 f1 = buf[ky * CST + cc];
        float2 f2 = buf[my * CST + mir_of(k, cc)];
        float xr = 0.5f * (f1.x + f2.x), xi = 0.5f * (f1.y - f2.y);
        float yr = 0.5f * (f1.y + f2.y), yi = 0.5f * (f2.x - f1.x);
        base[((size_t)ky << 10) + col_of(k, cc)] =
            make_float2((xr * xr + xi * xi) * inv, (yr * yr + yi * yi) * inv);
    }
}

// Pass 3: radial sums over the half-plane (ky<=512) with weight 2
// (self-mirror pixels weight 1), 4x-replicated LDS histograms.
__global__ __launch_bounds__(256) void radial_hist(const float2* __restrict__ spec,
                                                   float* __restrict__ sums,
                                                   float* __restrict__ counts) {
    __shared__ float hs0[4 * NBINS], hs1[4 * NBINS], hc[4 * NBINS];
    int tid = threadIdx.x, blk = blockIdx.x;
    int p = blk / 65, g = blk % 65;
    for (int i = tid; i < 4 * NBINS; i += 256) { hs0[i] = 0.f; hs1[i] = 0.f; hc[i] = 0.f; }
    __syncthreads();
    const float2* sp = spec + ((size_t)p << 20);
    int rep = (tid & 3) * NBINS;
    for (int q = 0; q < 32; ++q) {
        int idx = (q << 8) + tid;
        int ky = (g << 3) + (idx >> 10);
        int x = idx & 1023;
        if (ky > 512) continue;
        bool edge_k = (ky & 511) == 0;
        if (edge_k && x > 512) continue;
        float w = (edge_k && (x & 511) == 0) ? 1.f : 2.f;
        int bin = radial_bin(ky, x);
        float2 pv = sp[((size_t)ky << 10) + x];
        atomicAdd(&hs0[rep + bin], w * pv.x);
        atomicAdd(&hs1[rep + bin], w * pv.y);
        if (p == 0) atomicAdd(&hc[rep + bin], w);
    }
    __syncthreads();
    for (int i = tid; i < NBINS; i += 256) {
        float s0 = hs0[i] + hs0[NBINS + i] + hs0[2 * NBINS + i] + hs0[3 * NBINS + i];
        float s1 = hs1[i] + hs1[NBINS + i] + hs1[2 * NBINS + i] + hs1[3 * NBINS + i];
        if (s0 != 0.f) atomicAdd(&sums[(2 * p) * NBINS + i], s0);
        if (s1 != 0.f) atomicAdd(&sums[(2 * p + 1) * NBINS + i], s1);
        if (p == 0) {
            float cv = hc[i] + hc[NBINS + i] + hc[2 * NBINS + i] + hc[3 * NBINS + i];
            if (cv != 0.f) atomicAdd(&counts[i], cv);
        }
    }
}

// Pass 4: radial[b][k] = counts[k]>0 ? sums/max(counts,1) : 0
__global__ __launch_bounds__(256) void finalize_radial(const float* __restrict__ sums,
                                                       const float* __restrict__ counts,
                                                       float* __restrict__ radial) {
    int i = blockIdx.x * 256 + threadIdx.x;
    if (i < NB * NBINS) {
        float c = counts[i % NBINS];
        radial[i] = (c > 0.f) ? sums[i] / fmaxf(c, 1.f) : 0.f;
    }
}

// Pass 5: loss over half-plane with weight 2, radial rows in LDS.
__global__ __launch_bounds__(256) void loss_kernel(const float2* __restrict__ spec,
                                                   const float* __restrict__ radial,
                                                   float* __restrict__ out) {
    __shared__ float r0[NBINS], r1[NBINS];
    __shared__ float red[256];
    int tid = threadIdx.x, blk = blockIdx.x;
    int p = blk / 129, g = blk % 129;
    for (int i = tid; i < NBINS; i += 256) {
        r0[i] = radial[(2 * p) * NBINS + i];
        r1[i] = radial[(2 * p + 1) * NBINS + i];
    }
    __syncthreads();
    const float2* sp = spec + ((size_t)p << 20);
    float acc = 0.f;
    for (int q = 0; q < 16; ++q) {
        int idx = (q << 8) + tid;
        int ky = (g << 2) + (idx >> 10);
        int x = idx & 1023;
        if (ky > 512) continue;
        bool edge_k = (ky & 511) == 0;
        if (edge_k && x > 512) continue;
        float w = (edge_k && (x & 511) == 0) ? 1.f : 2.f;
        int bin = radial_bin(ky, x);
        float2 pv = sp[((size_t)ky << 10) + x];
        float dx_ = pv.x - r0[bin] + 1e-12f;
        float dy_ = pv.y - r1[bin] + 1e-12f;
        acc += w * (dx_ * dx_ + dy_ * dy_);
    }
    red[tid] = acc;
    __syncthreads();
    for (int s = 128; s > 0; s >>= 1) {
        if (tid < s) red[tid] += red[tid + s];
        __syncthreads();
    }
    if (tid == 0) atomicAdd(out, red[0] * (0.002f / 16.0f));
}

extern "C" void kernel_launch(void* const* d_in, const int* in_sizes, int n_in,
                              void* d_out, int out_size, void* d_ws, size_t ws_size,
                              hipStream_t stream) {
    const float* in = (const float*)d_in[0];
    float* out = (float*)d_out;
    char* ws = (char*)d_ws;

    float2* spec  = (float2*)ws;                                  // 64 MiB
    float* sums   = (float*)(ws + ((size_t)NPAIR << 20) * sizeof(float2));
    float* counts = sums + NB * NBINS;
    float* radial = counts + NBINS;

    hipMemsetAsync(sums, 0, (size_t)(NB * NBINS + NBINS) * sizeof(float), stream);
    hipMemsetAsync(out, 0, sizeof(float), stream);

    fft_rows<<<NPAIR * 1024, 256, 0, stream>>>(in, spec);
    fft_cols_pow<<<NPAIR * 128, 256, 0, stream>>>(spec);
    radial_hist<<<NPAIR * 65, 256, 0, stream>>>(spec, sums, counts);
    finalize_radial<<<(NB * NBINS + 255) / 256, 256, 0, stream>>>(sums, counts, radial);
    loss_kernel<<<NPAIR * 129, 256, 0, stream>>>(spec, radial, out);
}

// Round 4
// 213.357 us; speedup vs baseline: 2.4200x; 1.2328x over previous
//
#include <hip/hip_runtime.h>
#include <math.h>

#define NB 16
#define NPAIR 8
#define NBINS 725
#define NPIX (1024*1024)

// Skewed LDS slot map: 4 lanes per bank-pair (b64 floor) for every access
// pattern used below. slot(idx,c) = idx*9 + c + (idx>>5), idx in [0,1024), c in [0,8).
#define SLOT(idx, c) ((idx)*9 + (c) + ((idx)>>5))
#define SH_SIZE 9248   // max slot 9245

__device__ __forceinline__ constexpr int rev5(int j) {
    return ((j&1)<<4) | ((j&2)<<2) | (j&4) | ((j&8)>>2) | ((j&16)>>4);
}

// Fully-unrolled in-register 32-point FFT (input bit-reversed, output natural).
__device__ __forceinline__ void fft32(float2* r) {
    const float wr[16] = {1.f, 0.98078528f, 0.92387953f, 0.83146961f,
                          0.70710678f, 0.55557023f, 0.38268343f, 0.19509032f,
                          0.f, -0.19509032f, -0.38268343f, -0.55557023f,
                          -0.70710678f, -0.83146961f, -0.92387953f, -0.98078528f};
    const float wi[16] = {0.f, -0.19509032f, -0.38268343f, -0.55557023f,
                          -0.70710678f, -0.83146961f, -0.92387953f, -0.98078528f,
                          -1.f, -0.98078528f, -0.92387953f, -0.83146961f,
                          -0.70710678f, -0.55557023f, -0.38268343f, -0.19509032f};
    #pragma unroll
    for (int s = 1; s <= 5; ++s) {
        const int half = 1 << (s - 1);
        #pragma unroll
        for (int g = 0; g < 32; g += (1 << s)) {
            #pragma unroll
            for (int j = 0; j < half; ++j) {
                const float cw = wr[j << (5 - s)], sw = wi[j << (5 - s)];
                int i1 = g + j, i2 = i1 + half;
                float2 u = r[i1], v = r[i2];
                float2 vw = make_float2(v.x * cw - v.y * sw, v.x * sw + v.y * cw);
                r[i1] = make_float2(u.x + vw.x, u.y + vw.y);
                r[i2] = make_float2(u.x - vw.x, u.y - vw.y);
            }
        }
    }
}

// Twiddle by W_1024^(n1*k2), k2 = 0..31, via one sincos + recurrence.
__device__ __forceinline__ void twiddle1024(float2* r, int n1) {
    float sn, cs;
    sincosf((float)n1 * -0.006135923151542565f, &sn, &cs);
    float wx = 1.f, wy = 0.f;
    #pragma unroll
    for (int k2 = 0; k2 < 32; ++k2) {
        float2 s = r[k2];
        r[k2] = make_float2(s.x * wx - s.y * wy, s.x * wy + s.y * wx);
        float nx = wx * cs - wy * sn;
        wy = wx * sn + wy * cs;
        wx = nx;
    }
}

__device__ __forceinline__ int radial_bin(int ky, int kx) {
    int dy = ky - 512, dx = kx - 512;
    int d2 = dy * dy + dx * dx;
    int bin = (int)sqrtf((float)d2);
    if ((bin + 1) * (bin + 1) <= d2) ++bin;
    else if (bin * bin > d2) --bin;
    return bin;
}

// Mirror-paired column groups (bijection over 0..1023 across k=0..127).
__device__ __forceinline__ int col_of(int k, int c) {
    if (k == 0) return (c < 4) ? c : ((c == 4) ? 512 : 1028 - c);
    int a = k << 2;
    return (c < 4) ? (a + c) : (1017 + c - a);
}
__device__ __forceinline__ int mir_of(int k, int c) {
    if (k == 0) return (c == 0 || c == 4) ? c : ((c < 4) ? c + 4 : c - 4);
    return 7 - c;
}

// Pass 1: row FFTs, four-step 32x32. Block = 8 rows of one pair.
// Round 1 reads global directly (coalesced over n1); one barrier; round 2
// writes global directly (coalesced over k2).
__global__ __launch_bounds__(256, 2) void fft_rows(const float* __restrict__ in,
                                                   float2* __restrict__ spec) {
    __shared__ float2 sh[SH_SIZE];
    int tid = threadIdx.x, blk = blockIdx.x;
    int p = blk >> 7, y0 = (blk & 127) << 3;
    int n1 = tid & 31, c = tid >> 5;
    const float* xr = in + (((size_t)(2 * p)) << 20) + ((size_t)(y0 + c) << 10);
    const float* yr = xr + (1u << 20);
    float2 r[32];
    #pragma unroll
    for (int j = 0; j < 32; ++j) {
        int n = n1 + (rev5(j) << 5);
        r[j] = make_float2(xr[n], yr[n]);
    }
    fft32(r);
    twiddle1024(r, n1);
    int sb = 9 * n1 + c;                      // slot(32*k2+n1, c) = sb + 289*k2
    #pragma unroll
    for (int k2 = 0; k2 < 32; ++k2) sh[sb + 289 * k2] = r[k2];
    __syncthreads();
    int k2 = tid & 31;
    int rb = 289 * k2 + c;                    // slot(32*k2+n1, c) = rb + 9*n1
    #pragma unroll
    for (int j = 0; j < 32; ++j) r[j] = sh[rb + 9 * rev5(j)];
    fft32(r);
    float2* orow = spec + (((size_t)p) << 20) + ((size_t)(y0 + c) << 10) + k2;
    #pragma unroll
    for (int k1 = 0; k1 < 32; ++k1) orow[k1 << 5] = r[k1];
}

// Pass 2: column FFTs (four-step) on mirror-paired column groups + Hermitian
// power split, written in place as float2(power_even, power_odd).
__global__ __launch_bounds__(256, 2) void fft_cols_pow(float2* __restrict__ spec) {
    __shared__ float2 sh[SH_SIZE];
    int tid = threadIdx.x, blk = blockIdx.x;
    int p = blk >> 7, k = blk & 127;
    float2* base = spec + (((size_t)p) << 20);
    // stage tile: rows coalesced
    for (int rep = 0; rep < 32; ++rep) {
        int jdx = (rep << 8) + tid;
        int i = jdx >> 3, cc = jdx & 7;
        sh[SLOT(i, cc)] = base[((size_t)i << 10) + col_of(k, cc)];
    }
    __syncthreads();
    // round 1: FFT over n2 (each thread owns residue class n1 of column c)
    int n1 = tid & 31, c = tid >> 5;
    float2 r[32];
    int sb = 9 * n1 + c;
    #pragma unroll
    for (int j = 0; j < 32; ++j) r[j] = sh[sb + 289 * rev5(j)];
    fft32(r);
    twiddle1024(r, n1);
    #pragma unroll
    for (int k2 = 0; k2 < 32; ++k2) sh[sb + 289 * k2] = r[k2];
    __syncthreads();
    // round 2: FFT over n1 (each thread owns block k2 of column c)
    int k2 = tid & 31;
    int rb = 289 * k2 + c;
    #pragma unroll
    for (int j = 0; j < 32; ++j) r[j] = sh[rb + 9 * rev5(j)];
    fft32(r);
    __syncthreads();                          // all round-2 reads done
    int wb = 9 * k2 + c;                      // slot(k2+32*k1, c) = wb + 289*k1
    #pragma unroll
    for (int k1 = 0; k1 < 32; ++k1) sh[wb + 289 * k1] = r[k1];
    __syncthreads();
    // epilogue: Hermitian split -> per-batch powers, in-place overwrite
    const float inv = 1.0f / (float)NPIX;
    for (int rep = 0; rep < 32; ++rep) {
        int jdx = (rep << 8) + tid;
        int ky = jdx >> 3, cc = jdx & 7;
        int my = (1024 - ky) & 1023;
        float2 f1 = sh[SLOT(ky, cc)];
        float2 f2 = sh[SLOT(my, mir_of(k, cc))];
        float xr = 0.5f * (f1.x + f2.x), xi = 0.5f * (f1.y - f2.y);
        float yr = 0.5f * (f1.y + f2.y), yi = 0.5f * (f2.x - f1.x);
        base[((size_t)ky << 10) + col_of(k, cc)] =
            make_float2((xr * xr + xi * xi) * inv, (yr * yr + yi * yi) * inv);
    }
}

// Pass 3: radial sums over the half-plane (ky<=512) with weight 2
// (self-mirror pixels weight 1), 4x-replicated LDS histograms.
__global__ __launch_bounds__(256) void radial_hist(const float2* __restrict__ spec,
                                                   float* __restrict__ sums,
                                                   float* __restrict__ counts) {
    __shared__ float hs0[4 * NBINS], hs1[4 * NBINS], hc[4 * NBINS];
    int tid = threadIdx.x, blk = blockIdx.x;
    int p = blk / 65, g = blk % 65;
    for (int i = tid; i < 4 * NBINS; i += 256) { hs0[i] = 0.f; hs1[i] = 0.f; hc[i] = 0.f; }
    __syncthreads();
    const float2* sp = spec + ((size_t)p << 20);
    int rep = (tid & 3) * NBINS;
    for (int q = 0; q < 32; ++q) {
        int idx = (q << 8) + tid;
        int ky = (g << 3) + (idx >> 10);
        int x = idx & 1023;
        if (ky > 512) continue;
        bool edge_k = (ky & 511) == 0;
        if (edge_k && x > 512) continue;
        float w = (edge_k && (x & 511) == 0) ? 1.f : 2.f;
        int bin = radial_bin(ky, x);
        float2 pv = sp[((size_t)ky << 10) + x];
        atomicAdd(&hs0[rep + bin], w * pv.x);
        atomicAdd(&hs1[rep + bin], w * pv.y);
        if (p == 0) atomicAdd(&hc[rep + bin], w);
    }
    __syncthreads();
    for (int i = tid; i < NBINS; i += 256) {
        float s0 = hs0[i] + hs0[NBINS + i] + hs0[2 * NBINS + i] + hs0[3 * NBINS + i];
        float s1 = hs1[i] + hs1[NBINS + i] + hs1[2 * NBINS + i] + hs1[3 * NBINS + i];
        if (s0 != 0.f) atomicAdd(&sums[(2 * p) * NBINS + i], s0);
        if (s1 != 0.f) atomicAdd(&sums[(2 * p + 1) * NBINS + i], s1);
        if (p == 0) {
            float cv = hc[i] + hc[NBINS + i] + hc[2 * NBINS + i] + hc[3 * NBINS + i];
            if (cv != 0.f) atomicAdd(&counts[i], cv);
        }
    }
}

// Pass 4: radial[b][k] = counts[k]>0 ? sums/max(counts,1) : 0
__global__ __launch_bounds__(256) void finalize_radial(const float* __restrict__ sums,
                                                       const float* __restrict__ counts,
                                                       float* __restrict__ radial) {
    int i = blockIdx.x * 256 + threadIdx.x;
    if (i < NB * NBINS) {
        float c = counts[i % NBINS];
        radial[i] = (c > 0.f) ? sums[i] / fmaxf(c, 1.f) : 0.f;
    }
}

// Pass 5: loss over half-plane with weight 2, radial rows in LDS.
__global__ __launch_bounds__(256) void loss_kernel(const float2* __restrict__ spec,
                                                   const float* __restrict__ radial,
                                                   float* __restrict__ out) {
    __shared__ float r0[NBINS], r1[NBINS];
    __shared__ float red[256];
    int tid = threadIdx.x, blk = blockIdx.x;
    int p = blk / 129, g = blk % 129;
    for (int i = tid; i < NBINS; i += 256) {
        r0[i] = radial[(2 * p) * NBINS + i];
        r1[i] = radial[(2 * p + 1) * NBINS + i];
    }
    __syncthreads();
    const float2* sp = spec + ((size_t)p << 20);
    float acc = 0.f;
    for (int q = 0; q < 16; ++q) {
        int idx = (q << 8) + tid;
        int ky = (g << 2) + (idx >> 10);
        int x = idx & 1023;
        if (ky > 512) continue;
        bool edge_k = (ky & 511) == 0;
        if (edge_k && x > 512) continue;
        float w = (edge_k && (x & 511) == 0) ? 1.f : 2.f;
        int bin = radial_bin(ky, x);
        float2 pv = sp[((size_t)ky << 10) + x];
        float dx_ = pv.x - r0[bin] + 1e-12f;
        float dy_ = pv.y - r1[bin] + 1e-12f;
        acc += w * (dx_ * dx_ + dy_ * dy_);
    }
    red[tid] = acc;
    __syncthreads();
    for (int s = 128; s > 0; s >>= 1) {
        if (tid < s) red[tid] += red[tid + s];
        __syncthreads();
    }
    if (tid == 0) atomicAdd(out, red[0] * (0.002f / 16.0f));
}

extern "C" void kernel_launch(void* const* d_in, const int* in_sizes, int n_in,
                              void* d_out, int out_size, void* d_ws, size_t ws_size,
                              hipStream_t stream) {
    const float* in = (const float*)d_in[0];
    float* out = (float*)d_out;
    char* ws = (char*)d_ws;

    float2* spec  = (float2*)ws;                                  // 64 MiB
    float* sums   = (float*)(ws + ((size_t)NPAIR << 20) * sizeof(float2));
    float* counts = sums + NB * NBINS;
    float* radial = counts + NBINS;

    hipMemsetAsync(sums, 0, (size_t)(NB * NBINS + NBINS) * sizeof(float), stream);
    hipMemsetAsync(out, 0, sizeof(float), stream);

    fft_rows<<<NPAIR * 128, 256, 0, stream>>>(in, spec);
    fft_cols_pow<<<NPAIR * 128, 256, 0, stream>>>(spec);
    radial_hist<<<NPAIR * 65, 256, 0, stream>>>(spec, sums, counts);
    finalize_radial<<<(NB * NBINS + 255) / 256, 256, 0, stream>>>(sums, counts, radial);
    loss_kernel<<<NPAIR * 129, 256, 0, stream>>>(spec, radial, out);
}

// Round 5
// 201.640 us; speedup vs baseline: 2.5606x; 1.0581x over previous
//
#include <hip/hip_runtime.h>
#include <math.h>

#define NB 16
#define NPAIR 8
#define NBINS 725
#define NPIX (1024*1024)

// Skewed LDS slot map: slot(idx,c) = idx*9 + c + (idx>>5), idx in [0,1024), c in [0,8).
#define SLOT(idx, c) ((idx)*9 + (c) + ((idx)>>5))
#define SH_SIZE 9248   // max slot 9245

__device__ __forceinline__ constexpr int rev5(int j) {
    return ((j&1)<<4) | ((j&2)<<2) | (j&4) | ((j&8)>>2) | ((j&16)>>4);
}

// Fully-unrolled in-register 32-point FFT (input bit-reversed, output natural).
__device__ __forceinline__ void fft32(float2* r) {
    const float wr[16] = {1.f, 0.98078528f, 0.92387953f, 0.83146961f,
                          0.70710678f, 0.55557023f, 0.38268343f, 0.19509032f,
                          0.f, -0.19509032f, -0.38268343f, -0.55557023f,
                          -0.70710678f, -0.83146961f, -0.92387953f, -0.98078528f};
    const float wi[16] = {0.f, -0.19509032f, -0.38268343f, -0.55557023f,
                          -0.70710678f, -0.83146961f, -0.92387953f, -0.98078528f,
                          -1.f, -0.98078528f, -0.92387953f, -0.83146961f,
                          -0.70710678f, -0.55557023f, -0.38268343f, -0.19509032f};
    #pragma unroll
    for (int s = 1; s <= 5; ++s) {
        const int half = 1 << (s - 1);
        #pragma unroll
        for (int g = 0; g < 32; g += (1 << s)) {
            #pragma unroll
            for (int j = 0; j < half; ++j) {
                const float cw = wr[j << (5 - s)], sw = wi[j << (5 - s)];
                int i1 = g + j, i2 = i1 + half;
                float2 u = r[i1], v = r[i2];
                float2 vw = make_float2(v.x * cw - v.y * sw, v.x * sw + v.y * cw);
                r[i1] = make_float2(u.x + vw.x, u.y + vw.y);
                r[i2] = make_float2(u.x - vw.x, u.y - vw.y);
            }
        }
    }
}

// Twiddle by W_1024^(n1*k2), k2 = 0..31, via one sincos + recurrence.
__device__ __forceinline__ void twiddle1024(float2* r, int n1) {
    float sn, cs;
    sincosf((float)n1 * -0.006135923151542565f, &sn, &cs);
    float wx = 1.f, wy = 0.f;
    #pragma unroll
    for (int k2 = 0; k2 < 32; ++k2) {
        float2 s = r[k2];
        r[k2] = make_float2(s.x * wx - s.y * wy, s.x * wy + s.y * wx);
        float nx = wx * cs - wy * sn;
        wy = wx * sn + wy * cs;
        wx = nx;
    }
}

__device__ __forceinline__ int radial_bin(int ky, int kx) {
    int dy = ky - 512, dx = kx - 512;
    int d2 = dy * dy + dx * dx;
    int bin = (int)sqrtf((float)d2);
    if ((bin + 1) * (bin + 1) <= d2) ++bin;
    else if (bin * bin > d2) --bin;
    return bin;
}

// Mirror-paired column groups (bijection over 0..1023 across k=0..127).
__device__ __forceinline__ int col_of(int k, int c) {
    if (k == 0) return (c < 4) ? c : ((c == 4) ? 512 : 1028 - c);
    int a = k << 2;
    return (c < 4) ? (a + c) : (1017 + c - a);
}
__device__ __forceinline__ int mir_of(int k, int c) {
    if (k == 0) return (c == 0 || c == 4) ? c : ((c < 4) ? c + 4 : c - 4);
    return 7 - c;
}

// Pass 1: row FFTs (four-step 32x32), output written TRANSPOSED:
// spec_T[p][x][y] = F_row[p][y][x]. Transpose staged through the LDS tile.
__global__ __launch_bounds__(256, 2) void fft_rows(const float* __restrict__ in,
                                                   float2* __restrict__ spec) {
    __shared__ float2 sh[SH_SIZE];
    int tid = threadIdx.x, blk = blockIdx.x;
    int p = blk >> 7, y0 = (blk & 127) << 3;
    int n1 = tid & 31, c = tid >> 5;
    const float* xr = in + (((size_t)(2 * p)) << 20) + ((size_t)(y0 + c) << 10);
    const float* yr = xr + (1u << 20);
    float2 r[32];
    #pragma unroll
    for (int j = 0; j < 32; ++j) {
        int n = n1 + (rev5(j) << 5);
        r[j] = make_float2(xr[n], yr[n]);
    }
    fft32(r);
    twiddle1024(r, n1);
    int sb = 9 * n1 + c;                      // slot(32*k2+n1, c) = sb + 289*k2
    #pragma unroll
    for (int k2 = 0; k2 < 32; ++k2) sh[sb + 289 * k2] = r[k2];
    __syncthreads();
    int k2 = tid & 31;
    int rb = 289 * k2 + c;
    #pragma unroll
    for (int j = 0; j < 32; ++j) r[j] = sh[rb + 9 * rev5(j)];
    fft32(r);
    __syncthreads();                          // all round-2 reads done
    int wb = 9 * k2 + c;                      // slot(k2+32*k1, c) = wb + 289*k1
    #pragma unroll
    for (int k1 = 0; k1 < 32; ++k1) sh[wb + 289 * k1] = r[k1];
    __syncthreads();
    // write transposed: spec_T[k][y0+cc]
    float2* base = spec + (((size_t)p) << 20);
    for (int rep = 0; rep < 32; ++rep) {
        int idx = (rep << 8) + tid;
        int kcol = idx >> 3, cc = idx & 7;
        base[((size_t)kcol << 10) + y0 + cc] = sh[SLOT(kcol, cc)];
    }
}

// Pass 2: column FFTs (reading transposed spec = contiguous), Hermitian power
// split, fused radial histogram + per-batch sum(P^2). Writes only atomics.
__global__ __launch_bounds__(256, 2) void fft_cols_hist(const float2* __restrict__ spec,
                                                        float* __restrict__ sums,
                                                        float* __restrict__ sumP2) {
    __shared__ float2 sh[SH_SIZE];
    __shared__ float hs0[NBINS], hs1[NBINS];
    int tid = threadIdx.x, blk = blockIdx.x;
    int p = blk >> 7, k = blk & 127;
    for (int i = tid; i < NBINS; i += 256) { hs0[i] = 0.f; hs1[i] = 0.f; }
    const float2* base = spec + (((size_t)p) << 20);
    // stage tile: spec_T rows (= original columns) are contiguous
    for (int rep = 0; rep < 32; ++rep) {
        int idx = (rep << 8) + tid;
        int cc = idx >> 10, i = idx & 1023;
        sh[SLOT(i, cc)] = base[((size_t)col_of(k, cc) << 10) + i];
    }
    __syncthreads();
    // round 1: FFT over y within residue class n1
    int n1 = tid & 31, c = tid >> 5;
    float2 r[32];
    int sb = 9 * n1 + c;
    #pragma unroll
    for (int j = 0; j < 32; ++j) r[j] = sh[sb + 289 * rev5(j)];
    fft32(r);
    twiddle1024(r, n1);
    #pragma unroll
    for (int k2 = 0; k2 < 32; ++k2) sh[sb + 289 * k2] = r[k2];
    __syncthreads();
    // round 2
    int k2 = tid & 31;
    int rb = 289 * k2 + c;
    #pragma unroll
    for (int j = 0; j < 32; ++j) r[j] = sh[rb + 9 * rev5(j)];
    fft32(r);
    __syncthreads();
    int wb = 9 * k2 + c;
    #pragma unroll
    for (int k1 = 0; k1 < 32; ++k1) sh[wb + 289 * k1] = r[k1];
    __syncthreads();
    // epilogue: Hermitian split -> powers; half-plane (ky<=512) weighted hist
    // + sum(P^2). DC pixel (ky=0, x=0) skipped entirely (its loss term is 0).
    const float inv = 1.0f / (float)NPIX;
    float s2e = 0.f, s2o = 0.f;
    for (int cc = 0; cc < 8; ++cc) {
        int x = col_of(k, cc), mc = mir_of(k, cc);
        for (int ky = tid; ky < 513; ky += 256) {
            bool ek = (ky & 511) == 0;
            if (ek && x > 512) continue;
            if (ky == 0 && x == 0) continue;          // DC
            float w = (ek && (x & 511) == 0) ? 1.f : 2.f;
            int my = (1024 - ky) & 1023;
            float2 f1 = sh[SLOT(ky, cc)];
            float2 f2 = sh[SLOT(my, mc)];
            float xrr = 0.5f * (f1.x + f2.x), xii = 0.5f * (f1.y - f2.y);
            float yrr = 0.5f * (f1.y + f2.y), yii = 0.5f * (f2.x - f1.x);
            float pe = (xrr * xrr + xii * xii) * inv;
            float po = (yrr * yrr + yii * yii) * inv;
            int bin = radial_bin(ky, x);
            atomicAdd(&hs0[bin], w * pe);
            atomicAdd(&hs1[bin], w * po);
            s2e += w * pe * pe;
            s2o += w * po * po;
        }
    }
    #pragma unroll
    for (int off = 32; off > 0; off >>= 1) {
        s2e += __shfl_down(s2e, off);
        s2o += __shfl_down(s2o, off);
    }
    if ((tid & 63) == 0) {
        atomicAdd(&sumP2[2 * p], s2e);
        atomicAdd(&sumP2[2 * p + 1], s2o);
    }
    __syncthreads();
    for (int i = tid; i < NBINS; i += 256) {
        if (hs0[i] != 0.f) atomicAdd(&sums[(2 * p) * NBINS + i], hs0[i]);
        if (hs1[i] != 0.f) atomicAdd(&sums[(2 * p + 1) * NBINS + i], hs1[i]);
    }
}

// Geometry-only weighted bin counts over the half-plane (DC skipped).
__global__ __launch_bounds__(256) void radial_counts(float* __restrict__ counts) {
    __shared__ float hc[NBINS];
    int tid = threadIdx.x;
    int ky = blockIdx.x;                      // 0..512
    for (int i = tid; i < NBINS; i += 256) hc[i] = 0.f;
    __syncthreads();
    bool ek = (ky & 511) == 0;
    for (int x = tid; x < 1024; x += 256) {
        if (ek && x > 512) continue;
        if (ky == 0 && x == 0) continue;
        float w = (ek && (x & 511) == 0) ? 1.f : 2.f;
        atomicAdd(&hc[radial_bin(ky, x)], w);
    }
    __syncthreads();
    for (int i = tid; i < NBINS; i += 256)
        if (hc[i] != 0.f) atomicAdd(&counts[i], hc[i]);
}

// Final: loss = WA/B * sum_b [ sumP2[b] - sum_bins S^2/cnt ]
__global__ __launch_bounds__(256) void final_loss(const float* __restrict__ sums,
                                                  const float* __restrict__ counts,
                                                  const float* __restrict__ sumP2,
                                                  float* __restrict__ out) {
    __shared__ float red[256];
    int tid = threadIdx.x;
    float acc = 0.f;
    for (int b = 0; b < NB; ++b) {
        float part = 0.f;
        for (int i = tid; i < NBINS; i += 256) {
            float cv = counts[i];
            float s = sums[b * NBINS + i];
            if (cv > 0.f) part += s * s / cv;
        }
        red[tid] = part;
        __syncthreads();
        for (int s = 128; s > 0; s >>= 1) {
            if (tid < s) red[tid] += red[tid + s];
            __syncthreads();
        }
        if (tid == 0) acc += sumP2[b] - red[0];
        __syncthreads();
    }
    if (tid == 0) out[0] = acc * (0.002f / 16.0f);
}

extern "C" void kernel_launch(void* const* d_in, const int* in_sizes, int n_in,
                              void* d_out, int out_size, void* d_ws, size_t ws_size,
                              hipStream_t stream) {
    const float* in = (const float*)d_in[0];
    float* out = (float*)d_out;
    char* ws = (char*)d_ws;

    float2* spec  = (float2*)ws;                                  // 64 MiB
    float* sums   = (float*)(ws + ((size_t)NPAIR << 20) * sizeof(float2));
    float* counts = sums + NB * NBINS;
    float* sumP2  = counts + NBINS;

    hipMemsetAsync(sums, 0, (size_t)(NB * NBINS + NBINS + NB) * sizeof(float), stream);

    fft_rows<<<NPAIR * 128, 256, 0, stream>>>(in, spec);
    radial_counts<<<513, 256, 0, stream>>>(counts);
    fft_cols_hist<<<NPAIR * 128, 256, 0, stream>>>(spec, sums, sumP2);
    final_loss<<<1, 256, 0, stream>>>(sums, counts, sumP2, out);
}